// Round 7
// baseline (289.622 us; speedup 1.0000x reference)
//
#include <hip/hip_runtime.h>

typedef unsigned short u16;
typedef unsigned int u32;
typedef short bf16x8 __attribute__((ext_vector_type(8)));
typedef float f32x4 __attribute__((ext_vector_type(4)));
typedef unsigned short u16x4 __attribute__((ext_vector_type(4)));
typedef unsigned short u16x8 __attribute__((ext_vector_type(8)));

__device__ __forceinline__ u16 f32_to_bf16(float f) {
    u32 u = __float_as_uint(f);
    u += 0x7FFFu + ((u >> 16) & 1u);
    return (u16)(u >> 16);
}
// truncating cast (p in [0,1], P-matrix only)
__device__ __forceinline__ short f32_to_bf16_trunc(float f) {
    return (short)(__float_as_uint(f) >> 16);
}

// async global->LDS, 16B per lane; lds pointer must be wave-uniform
__device__ __forceinline__ void gl_lds16(const u16* g, u16* l) {
    __builtin_amdgcn_global_load_lds(
        (const __attribute__((address_space(1))) u32*)g,
        (__attribute__((address_space(3))) u32*)l, 16, 0, 0);
}

// ---------------------------------------------------------------------------
// bulk fp32 -> bf16 cast
// ---------------------------------------------------------------------------
struct CastArgs {
    const float* src[7];
    u16* dst[7];
    int n4[7];
};

__global__ __launch_bounds__(256) void cast_kernel(CastArgs a) {
    const int y = blockIdx.y;
    const float* s = a.src[y];
    u16* d = a.dst[y];
    const int n4 = a.n4[y];
    for (int i = blockIdx.x * blockDim.x + threadIdx.x; i < n4; i += gridDim.x * blockDim.x) {
        f32x4 v = *(const f32x4*)&s[(size_t)i * 4];
        u16x4 o = { f32_to_bf16(v[0]), f32_to_bf16(v[1]), f32_to_bf16(v[2]), f32_to_bf16(v[3]) };
        *(u16x4*)&d[(size_t)i * 4] = o;
    }
}

#define GK 1024
#define GN 1024
#define GM 4096

// ---------------------------------------------------------------------------
// QKV projection GEMM + RoPE. 128x128 tile, BK=32, grid (32 m, 8 n, 3 z).
// z=0 Q: normal [t][HD] bf16, scaled 1/8.
// z=1 K: KT[h][kb][ks][kl][32]   (dk split in halves ks -> 64 B LDS rows)
// z=2 V: VT[h][kb][ks][dv][32']  (key halves; kappa permutation in slot idx)
// ---------------------------------------------------------------------------
__global__ __launch_bounds__(256) void gemm_rope(
    const u16* __restrict__ A0, const u16* __restrict__ A1, const u16* __restrict__ A2,
    const u16* __restrict__ W0, const u16* __restrict__ W1, const u16* __restrict__ W2,
    u16* __restrict__ C0, u16* __restrict__ C1, u16* __restrict__ C2,
    const float* __restrict__ freqs)
{
    __shared__ u16 SM[8192];
    u16* As = SM;
    u16* Bs = SM + 4096;

    const int z = blockIdx.z;
    const u16* A = (z == 0) ? A0 : ((z == 1) ? A1 : A2);
    const u16* W = (z == 0) ? W0 : ((z == 1) ? W1 : W2);
    u16* Cb      = (z == 0) ? C0 : ((z == 1) ? C1 : C2);
    const float ascale = (z == 0) ? 0.125f : 1.0f;

    const int tid  = threadIdx.x;
    const int w    = tid >> 6;
    const int lane = tid & 63;
    const int quad = lane >> 4;
    const int l16  = lane & 15;
    const int m0 = blockIdx.x * 128;
    const int n0 = blockIdx.y * 128;
    const int wm = (w >> 1) * 64;
    const int wn = (w & 1) * 64;

    const int sr = tid >> 2;
    const int sc = (tid & 3) * 8;
    const size_t aoff0 = (size_t)(m0 + sr) * GK + sc;
    const size_t aoff1 = aoff0 + (size_t)64 * GK;
    const size_t boff0 = (size_t)(n0 + sr) * GK + sc;
    const size_t boff1 = boff0 + (size_t)64 * GK;
    u16* ldsA0 = &As[w * 512];
    u16* ldsA1 = &As[2048 + w * 512];
    u16* ldsB0 = &Bs[w * 512];
    u16* ldsB1 = &Bs[2048 + w * 512];

    f32x4 acc[4][4];
    for (int i = 0; i < 4; i++)
        for (int j = 0; j < 4; j++) acc[i][j] = 0.f;

    for (int k0 = 0; k0 < GK; k0 += 32) {
        gl_lds16(A + aoff0 + k0, ldsA0);
        gl_lds16(A + aoff1 + k0, ldsA1);
        gl_lds16(W + boff0 + k0, ldsB0);
        gl_lds16(W + boff1 + k0, ldsB1);
        __syncthreads();

        bf16x8 af[4], bfr[4];
        for (int t = 0; t < 4; t++) {
            af[t]  = *(const bf16x8*)&As[(wm + t * 16 + l16) * 32 + quad * 8];
            bfr[t] = *(const bf16x8*)&Bs[(wn + t * 16 + l16) * 32 + quad * 8];
        }
        for (int mt = 0; mt < 4; mt++)
            for (int nt = 0; nt < 4; nt++)
                acc[mt][nt] = __builtin_amdgcn_mfma_f32_16x16x32_bf16(
                    af[mt], bfr[nt], acc[mt][nt], 0, 0, 0);
        __syncthreads();
    }
    // after final barrier As/Bs are dead; per-wave scratch (wave-private)
    u16* tr = SM + w * 1152;  // 16 rows x 72 u16

    const int hh = (n0 + wn) >> 6;
    const size_t tb = (size_t)hh * 262144 + (size_t)((m0 + wm) >> 6) * 4096;

    if (z != 2) {
        for (int mt = 0; mt < 4; mt++) {
            #pragma unroll
            for (int r = 0; r < 4; r++) {
                int m = m0 + wm + mt * 16 + quad * 4 + r;
                float v0 = acc[mt][0][r];
                float v1 = acc[mt][1][r];
                float f0 = freqs[m * 32 + l16];
                float f1 = freqs[m * 32 + 16 + l16];
                float s0, c0, s1, c1;
                __sincosf(f0, &s0, &c0);
                __sincosf(f1, &s1, &c1);
                int row = quad * 4 + r;
                tr[row * 72 + l16]      = f32_to_bf16((v0 * c0 - v1 * s0) * ascale);
                tr[row * 72 + 16 + l16] = f32_to_bf16((v1 * c1 + v0 * s1) * ascale);
                tr[row * 72 + 32 + l16] = f32_to_bf16(acc[mt][2][r] * ascale);
                tr[row * 72 + 48 + l16] = f32_to_bf16(acc[mt][3][r] * ascale);
            }
            // wave-private transpose read: lane -> row l16, cols quad*16..+16
            u16x8 va = *(const u16x8*)&tr[l16 * 72 + quad * 16];
            u16x8 vb = *(const u16x8*)&tr[l16 * 72 + quad * 16 + 8];
            if (z == 0) {
                size_t base = (size_t)(m0 + wm + mt * 16 + l16) * GN + n0 + wn + quad * 16;
                *(u16x8*)&Cb[base]     = va;
                *(u16x8*)&Cb[base + 8] = vb;
            } else {
                // K half-split: dk = quad*16 + c -> half ks = quad>>1, within = (quad&1)*16 + c
                size_t base = tb + (size_t)(quad >> 1) * 2048
                            + (size_t)(mt * 16 + l16) * 32 + (quad & 1) * 16;
                *(u16x8*)&Cb[base]     = va;
                *(u16x8*)&Cb[base + 8] = vb;
            }
        }
    } else {
        // V: VT[h][kb][ks][dv][32'], kappa within each 32-key half
        for (int mt = 0; mt < 4; mt++) {
            float o0[4], o1[4];
            for (int r = 0; r < 4; r++) {
                int m = m0 + wm + mt * 16 + quad * 4 + r;
                float v0 = acc[mt][0][r];
                float v1 = acc[mt][1][r];
                float f0 = freqs[m * 32 + l16];
                float f1 = freqs[m * 32 + 16 + l16];
                float s0, c0, s1, c1;
                __sincosf(f0, &s0, &c0);
                __sincosf(f1, &s1, &c1);
                o0[r] = v0 * c0 - v1 * s0;
                o1[r] = v1 * c1 + v0 * s1;
            }
            const int ks = mt >> 1;                       // key half
            const int sl = 4 * (mt & 1) + 8 * quad;       // slot within half (r adds 0..3)
            const size_t hb = tb + (size_t)ks * 2048 + sl;
            u16x4 u;
            u = { f32_to_bf16(o0[0]), f32_to_bf16(o0[1]), f32_to_bf16(o0[2]), f32_to_bf16(o0[3]) };
            *(u16x4*)&Cb[hb + (size_t)l16 * 32] = u;
            u = { f32_to_bf16(o1[0]), f32_to_bf16(o1[1]), f32_to_bf16(o1[2]), f32_to_bf16(o1[3]) };
            *(u16x4*)&Cb[hb + (size_t)(16 + l16) * 32] = u;
            u = { f32_to_bf16(acc[mt][2][0]), f32_to_bf16(acc[mt][2][1]),
                  f32_to_bf16(acc[mt][2][2]), f32_to_bf16(acc[mt][2][3]) };
            *(u16x4*)&Cb[hb + (size_t)(32 + l16) * 32] = u;
            u = { f32_to_bf16(acc[mt][3][0]), f32_to_bf16(acc[mt][3][1]),
                  f32_to_bf16(acc[mt][3][2]), f32_to_bf16(acc[mt][3][3]) };
            *(u16x4*)&Cb[hb + (size_t)(48 + l16) * 32] = u;
        }
    }
}

// ---------------------------------------------------------------------------
// Output projection GEMM, no split-K. Tile 64x128, grid (64 m, 8 n) = 512
// blocks = 2/CU. Full K=1024 loop, fp32 stores direct to d_out.
// 4 waves: wave (w>>1) -> 32 m rows, (w&1) -> 64 n cols. 8 MFMA/wave/iter.
// ---------------------------------------------------------------------------
__global__ __launch_bounds__(256) void gemm_out(
    const u16* __restrict__ A, const u16* __restrict__ W, float* __restrict__ C)
{
    __shared__ u16 SM[8704];   // staging 6144 u16 (A 2048 | B 4096); tr 17408 B
    u16* As = SM;              // 64 x 32
    u16* Bs = SM + 2048;       // 128 x 32

    const int tid  = threadIdx.x;
    const int w    = tid >> 6;
    const int lane = tid & 63;
    const int quad = lane >> 4;
    const int l16  = lane & 15;
    const int m0 = blockIdx.x * 64;
    const int n0 = blockIdx.y * 128;
    const int wm = (w >> 1) * 32;
    const int wn = (w & 1) * 64;

    const size_t aoff  = (size_t)(m0 + (tid >> 2)) * GK + (tid & 3) * 8;
    const size_t boff0 = (size_t)(n0 + (tid >> 2)) * GK + (tid & 3) * 8;
    const size_t boff1 = boff0 + (size_t)64 * GK;
    u16* ldsA  = &As[w * 512];
    u16* ldsB0 = &Bs[w * 512];
    u16* ldsB1 = &Bs[2048 + w * 512];

    f32x4 acc[2][4];
    for (int i = 0; i < 2; i++)
        for (int j = 0; j < 4; j++) acc[i][j] = 0.f;

    for (int k0 = 0; k0 < GK; k0 += 32) {
        gl_lds16(A + aoff + k0, ldsA);
        gl_lds16(W + boff0 + k0, ldsB0);
        gl_lds16(W + boff1 + k0, ldsB1);
        __syncthreads();

        bf16x8 af[2], bfr[4];
        for (int t = 0; t < 2; t++)
            af[t] = *(const bf16x8*)&As[(wm + t * 16 + l16) * 32 + quad * 8];
        for (int t = 0; t < 4; t++)
            bfr[t] = *(const bf16x8*)&Bs[(wn + t * 16 + l16) * 32 + quad * 8];
        for (int mt = 0; mt < 2; mt++)
            for (int nt = 0; nt < 4; nt++)
                acc[mt][nt] = __builtin_amdgcn_mfma_f32_16x16x32_bf16(
                    af[mt], bfr[nt], acc[mt][nt], 0, 0, 0);
        __syncthreads();
    }

    // per-wave fp32 transpose scratch: 16 rows x 68 floats
    float* tr = (float*)SM + w * 1088;
    for (int mt = 0; mt < 2; mt++) {
        #pragma unroll
        for (int nt = 0; nt < 4; nt++)
            #pragma unroll
            for (int r = 0; r < 4; r++)
                tr[(quad * 4 + r) * 68 + nt * 16 + l16] = acc[mt][nt][r];
        size_t base = (size_t)(m0 + wm + mt * 16 + l16) * GN + n0 + wn + quad * 16;
        #pragma unroll
        for (int c = 0; c < 4; c++) {
            f32x4 v = *(const f32x4*)&tr[l16 * 68 + quad * 16 + c * 4];
            *(f32x4*)&C[base + c * 4] = v;
        }
    }
}

// ---------------------------------------------------------------------------
// Flash attention, causal. Grid 512 x 256 thr (4 waves).
// Block = one 128-q-row granule g of head h; wave w owns 32 rows
// [128g + 32w, +32) as TWO Q B-frags -> each K/V ds_read_b128 feeds 2 MFMAs
// (halves LDS-port traffic per FLOP vs 16 q/wave). Iters = 2g+2; granule
// order interleaved (0,31,1,30,...) so co-resident blocks balance.
// K/V staged per block via global_load_lds into 32 KB LDS double buffer,
// DMA for kb+1 issued right after the top barrier. Waves 0,1 skip the final
// half-diagonal tile (their rows end 64 keys earlier). Fixed-max softmax
// (exp(s-16)); P repacked register-only into PV B-operand (V pre-permuted
// per 32-key half by gemm_rope).
// ---------------------------------------------------------------------------
__global__ __launch_bounds__(256, 2) void attn_kernel(
    const u16* __restrict__ Qb, const u16* __restrict__ KT,
    const u16* __restrict__ VTg, u16* __restrict__ valsb)
{
    __shared__ u16 KV[2][8192];      // [buf][ K 4096 | V 4096 ] u16
    __shared__ float Ow[4][32 * 68]; // per-wave epilogue transpose

    const int tid  = threadIdx.x;
    const int w    = tid >> 6;
    const int lane = tid & 63;
    const int quad = lane >> 4;
    const int l16  = lane & 15;
    const int HD = 1024;

    const int id  = blockIdx.x;
    const int h   = (id & 7) * 2 + ((id >> 3) & 1);
    const int idx = id >> 4;                                   // 0..31
    const int g   = (idx & 1) ? (31 - (idx >> 1)) : (idx >> 1); // long/short interleave

    const u16* kt = KT  + (size_t)h * 262144;
    const u16* vt = VTg + (size_t)h * 262144;

    const int kb_end  = 2 * g + 1;          // last tile staged
    const int kb_diag = 2 * g + (w >> 1);   // this wave's diagonal tile
    const int qbase   = (w & 1) * 32;       // row offset within wave-pair's 64

    // Q B-frags: rows 128g + 32w + qt*16 + l16
    bf16x8 bq[2][2];
    #pragma unroll
    for (int qt = 0; qt < 2; qt++)
        #pragma unroll
        for (int ks = 0; ks < 2; ks++)
            bq[qt][ks] = *(const bf16x8*)&Qb[(size_t)(128 * g + 32 * w + qt * 16 + l16) * HD
                                             + h * 64 + ks * 32 + quad * 8];

    f32x4 o[2][4];
    #pragma unroll
    for (int qt = 0; qt < 2; qt++)
        #pragma unroll
        for (int nv = 0; nv < 4; nv++) o[qt][nv] = 0.f;
    float lsum[2] = { 0.f, 0.f };

    // prologue DMA: tile 0 -> buf 0
    #pragma unroll
    for (int i = 0; i < 2; i++) {
        gl_lds16(kt + i * 2048 + w * 512 + lane * 8, &KV[0][i * 2048 + w * 512]);
        gl_lds16(vt + i * 2048 + w * 512 + lane * 8, &KV[0][4096 + i * 2048 + w * 512]);
    }

    for (int kb = 0; kb <= kb_end; kb++) {
        __syncthreads();  // DMA for kb drained; buf[(kb+1)&1] free
        if (kb < kb_end) {
            const int nb = (kb + 1) & 1;
            const u16* ksrc = kt + (size_t)(kb + 1) * 4096;
            const u16* vsrc = vt + (size_t)(kb + 1) * 4096;
            #pragma unroll
            for (int i = 0; i < 2; i++) {
                gl_lds16(ksrc + i * 2048 + w * 512 + lane * 8, &KV[nb][i * 2048 + w * 512]);
                gl_lds16(vsrc + i * 2048 + w * 512 + lane * 8, &KV[nb][4096 + i * 2048 + w * 512]);
            }
        }
        if (kb > kb_diag) continue;  // waves 0,1 idle on the half-diagonal tile

        const u16* Ksb = &KV[kb & 1][0];
        const u16* Vsb = &KV[kb & 1][4096];

        // S^T = K * Q^T : key = nt*16 + quad*4 + r, q = qt*16 + l16
        f32x4 s[2][4];
        #pragma unroll
        for (int nt = 0; nt < 4; nt++) {
            bf16x8 ak0 = *(const bf16x8*)&Ksb[(nt * 16 + l16) * 32 + quad * 8];
            bf16x8 ak1 = *(const bf16x8*)&Ksb[2048 + (nt * 16 + l16) * 32 + quad * 8];
            #pragma unroll
            for (int qt = 0; qt < 2; qt++) {
                f32x4 z4 = { 0.f, 0.f, 0.f, 0.f };
                s[qt][nt] = __builtin_amdgcn_mfma_f32_16x16x32_bf16(ak0, bq[qt][0], z4, 0, 0, 0);
                s[qt][nt] = __builtin_amdgcn_mfma_f32_16x16x32_bf16(ak1, bq[qt][1], s[qt][nt], 0, 0, 0);
            }
        }

        if (kb == kb_diag) {  // diagonal tile: mask key > q
            #pragma unroll
            for (int qt = 0; qt < 2; qt++) {
                const int ql = qbase + qt * 16 + l16;
                #pragma unroll
                for (int nt = 0; nt < 4; nt++)
                    #pragma unroll
                    for (int r = 0; r < 4; r++)
                        if (nt * 16 + quad * 4 + r > ql) s[qt][nt][r] = -1e30f;
            }
        }

        // V frags issued before exp so lgkmcnt hides under VALU
        bf16x8 av[8];
        #pragma unroll
        for (int nv = 0; nv < 4; nv++) {
            av[nv * 2]     = *(const bf16x8*)&Vsb[(nv * 16 + l16) * 32 + quad * 8];
            av[nv * 2 + 1] = *(const bf16x8*)&Vsb[2048 + (nv * 16 + l16) * 32 + quad * 8];
        }

        #pragma unroll
        for (int qt = 0; qt < 2; qt++) {
            float ls = 0.f;
            #pragma unroll
            for (int nt = 0; nt < 4; nt++)
                #pragma unroll
                for (int r = 0; r < 4; r++) {
                    float pe = __expf(s[qt][nt][r] - 16.f);
                    s[qt][nt][r] = pe;
                    ls += pe;
                }
            lsum[qt] += ls;

            bf16x8 bp0 = { f32_to_bf16_trunc(s[qt][0][0]), f32_to_bf16_trunc(s[qt][0][1]),
                           f32_to_bf16_trunc(s[qt][0][2]), f32_to_bf16_trunc(s[qt][0][3]),
                           f32_to_bf16_trunc(s[qt][1][0]), f32_to_bf16_trunc(s[qt][1][1]),
                           f32_to_bf16_trunc(s[qt][1][2]), f32_to_bf16_trunc(s[qt][1][3]) };
            bf16x8 bp1 = { f32_to_bf16_trunc(s[qt][2][0]), f32_to_bf16_trunc(s[qt][2][1]),
                           f32_to_bf16_trunc(s[qt][2][2]), f32_to_bf16_trunc(s[qt][2][3]),
                           f32_to_bf16_trunc(s[qt][3][0]), f32_to_bf16_trunc(s[qt][3][1]),
                           f32_to_bf16_trunc(s[qt][3][2]), f32_to_bf16_trunc(s[qt][3][3]) };
            #pragma unroll
            for (int nv = 0; nv < 4; nv++) {
                o[qt][nv] = __builtin_amdgcn_mfma_f32_16x16x32_bf16(av[nv * 2], bp0, o[qt][nv], 0, 0, 0);
                o[qt][nv] = __builtin_amdgcn_mfma_f32_16x16x32_bf16(av[nv * 2 + 1], bp1, o[qt][nv], 0, 0, 0);
            }
        }
    }

    // epilogue: per-wave LDS transpose (wave-private region, no barrier)
    float linv[2];
    #pragma unroll
    for (int qt = 0; qt < 2; qt++) {
        float ls = lsum[qt];
        ls += __shfl_xor(ls, 16);
        ls += __shfl_xor(ls, 32);
        linv[qt] = 1.f / ls;
    }
    float* myOw = Ow[w];
    #pragma unroll
    for (int qt = 0; qt < 2; qt++)
        #pragma unroll
        for (int nv = 0; nv < 4; nv++)
            #pragma unroll
            for (int r = 0; r < 4; r++)
                myOw[(qt * 16 + l16) * 68 + nv * 16 + quad * 4 + r] = o[qt][nv][r] * linv[qt];
    #pragma unroll
    for (int i = 0; i < 8; i++) {
        int row = i * 4 + quad;  // q row within wave's 32
        f32x4 vv = *(const f32x4*)&myOw[row * 68 + l16 * 4];
        u16x4 u = { f32_to_bf16(vv[0]), f32_to_bf16(vv[1]), f32_to_bf16(vv[2]), f32_to_bf16(vv[3]) };
        *(u16x4*)&valsb[(size_t)(128 * g + 32 * w + row) * HD + h * 64 + l16 * 4] = u;
    }
}

// ---------------------------------------------------------------------------
// ws layout (u16 idx): qc 0 | kc 4M | vc 8M | wqc 12M | wkc 13M | wvc 14M |
// woc 15M | Qb 16M | KT 20M | VT 24M ; valsb reuses qc. Total 56 MiB.
// ---------------------------------------------------------------------------
extern "C" void kernel_launch(void* const* d_in, const int* in_sizes, int n_in,
                              void* d_out, int out_size, void* d_ws, size_t ws_size,
                              hipStream_t stream) {
    const float* q     = (const float*)d_in[0];
    const float* k     = (const float*)d_in[1];
    const float* v     = (const float*)d_in[2];
    const float* freqs = (const float*)d_in[4];
    const float* wq    = (const float*)d_in[5];
    const float* wk    = (const float*)d_in[6];
    const float* wv    = (const float*)d_in[7];
    const float* wo    = (const float*)d_in[8];

    u16* B = (u16*)d_ws;
    u16* qc  = B;
    u16* kc  = B + (size_t)4194304;
    u16* vc  = B + (size_t)8388608;
    u16* wqc = B + (size_t)12582912;
    u16* wkc = B + (size_t)13631488;
    u16* wvc = B + (size_t)14680064;
    u16* woc = B + (size_t)15728640;
    u16* Qb  = B + (size_t)16777216;
    u16* KT  = B + (size_t)20971520;
    u16* VT  = B + (size_t)25165824;
    u16* valsb = qc;   // qc dead after gemm_rope reads it

    CastArgs ca;
    ca.src[0] = q;  ca.dst[0] = qc;  ca.n4[0] = 1048576;
    ca.src[1] = k;  ca.dst[1] = kc;  ca.n4[1] = 1048576;
    ca.src[2] = v;  ca.dst[2] = vc;  ca.n4[2] = 1048576;
    ca.src[3] = wq; ca.dst[3] = wqc; ca.n4[3] = 262144;
    ca.src[4] = wk; ca.dst[4] = wkc; ca.n4[4] = 262144;
    ca.src[5] = wv; ca.dst[5] = wvc; ca.n4[5] = 262144;
    ca.src[6] = wo; ca.dst[6] = woc; ca.n4[6] = 262144;
    cast_kernel<<<dim3(1024, 7), 256, 0, stream>>>(ca);

    gemm_rope<<<dim3(32, 8, 3), 256, 0, stream>>>(
        qc, kc, vc, wqc, wkc, wvc, Qb, KT, VT, freqs);

    attn_kernel<<<dim3(512), 256, 0, stream>>>(Qb, KT, VT, valsb);

    gemm_out<<<dim3(64, 8), 256, 0, stream>>>(valsb, woc, (float*)d_out);
}

// Round 8
// 289.030 us; speedup vs baseline: 1.0020x; 1.0020x over previous
//
#include <hip/hip_runtime.h>

typedef unsigned short u16;
typedef unsigned int u32;
typedef short bf16x8 __attribute__((ext_vector_type(8)));
typedef float f32x4 __attribute__((ext_vector_type(4)));
typedef unsigned short u16x4 __attribute__((ext_vector_type(4)));
typedef unsigned short u16x8 __attribute__((ext_vector_type(8)));

__device__ __forceinline__ u16 f32_to_bf16(float f) {
    u32 u = __float_as_uint(f);
    u += 0x7FFFu + ((u >> 16) & 1u);
    return (u16)(u >> 16);
}
// truncating cast (p in [0,1], P-matrix only)
__device__ __forceinline__ short f32_to_bf16_trunc(float f) {
    return (short)(__float_as_uint(f) >> 16);
}

// async global->LDS, 16B per lane; lds pointer must be wave-uniform
__device__ __forceinline__ void gl_lds16(const u16* g, u16* l) {
    __builtin_amdgcn_global_load_lds(
        (const __attribute__((address_space(1))) u32*)g,
        (__attribute__((address_space(3))) u32*)l, 16, 0, 0);
}

// ---------------------------------------------------------------------------
// bulk fp32 -> bf16 cast
// ---------------------------------------------------------------------------
struct CastArgs {
    const float* src[7];
    u16* dst[7];
    int n4[7];
};

__global__ __launch_bounds__(256) void cast_kernel(CastArgs a) {
    const int y = blockIdx.y;
    const float* s = a.src[y];
    u16* d = a.dst[y];
    const int n4 = a.n4[y];
    for (int i = blockIdx.x * blockDim.x + threadIdx.x; i < n4; i += gridDim.x * blockDim.x) {
        f32x4 v = *(const f32x4*)&s[(size_t)i * 4];
        u16x4 o = { f32_to_bf16(v[0]), f32_to_bf16(v[1]), f32_to_bf16(v[2]), f32_to_bf16(v[3]) };
        *(u16x4*)&d[(size_t)i * 4] = o;
    }
}

#define GK 1024
#define GN 1024
#define GM 4096

// ---------------------------------------------------------------------------
// QKV projection GEMM + RoPE. 128x128 tile, BK=32, grid (32 m, 8 n, 3 z).
// z=0 Q: normal [t][HD] bf16, scaled 1/8.
// z=1 K: KT[h][kb][ks][kl][32]   (dk split in halves ks -> 64 B LDS rows)
// z=2 V: VT[h][kb][ks][dv][32']  (key halves; kappa permutation in slot idx)
// ---------------------------------------------------------------------------
__global__ __launch_bounds__(256) void gemm_rope(
    const u16* __restrict__ A0, const u16* __restrict__ A1, const u16* __restrict__ A2,
    const u16* __restrict__ W0, const u16* __restrict__ W1, const u16* __restrict__ W2,
    u16* __restrict__ C0, u16* __restrict__ C1, u16* __restrict__ C2,
    const float* __restrict__ freqs)
{
    __shared__ u16 SM[8192];
    u16* As = SM;
    u16* Bs = SM + 4096;

    const int z = blockIdx.z;
    const u16* A = (z == 0) ? A0 : ((z == 1) ? A1 : A2);
    const u16* W = (z == 0) ? W0 : ((z == 1) ? W1 : W2);
    u16* Cb      = (z == 0) ? C0 : ((z == 1) ? C1 : C2);
    const float ascale = (z == 0) ? 0.125f : 1.0f;

    const int tid  = threadIdx.x;
    const int w    = tid >> 6;
    const int lane = tid & 63;
    const int quad = lane >> 4;
    const int l16  = lane & 15;
    const int m0 = blockIdx.x * 128;
    const int n0 = blockIdx.y * 128;
    const int wm = (w >> 1) * 64;
    const int wn = (w & 1) * 64;

    const int sr = tid >> 2;
    const int sc = (tid & 3) * 8;
    const size_t aoff0 = (size_t)(m0 + sr) * GK + sc;
    const size_t aoff1 = aoff0 + (size_t)64 * GK;
    const size_t boff0 = (size_t)(n0 + sr) * GK + sc;
    const size_t boff1 = boff0 + (size_t)64 * GK;
    u16* ldsA0 = &As[w * 512];
    u16* ldsA1 = &As[2048 + w * 512];
    u16* ldsB0 = &Bs[w * 512];
    u16* ldsB1 = &Bs[2048 + w * 512];

    f32x4 acc[4][4];
    for (int i = 0; i < 4; i++)
        for (int j = 0; j < 4; j++) acc[i][j] = 0.f;

    for (int k0 = 0; k0 < GK; k0 += 32) {
        gl_lds16(A + aoff0 + k0, ldsA0);
        gl_lds16(A + aoff1 + k0, ldsA1);
        gl_lds16(W + boff0 + k0, ldsB0);
        gl_lds16(W + boff1 + k0, ldsB1);
        __syncthreads();

        bf16x8 af[4], bfr[4];
        for (int t = 0; t < 4; t++) {
            af[t]  = *(const bf16x8*)&As[(wm + t * 16 + l16) * 32 + quad * 8];
            bfr[t] = *(const bf16x8*)&Bs[(wn + t * 16 + l16) * 32 + quad * 8];
        }
        for (int mt = 0; mt < 4; mt++)
            for (int nt = 0; nt < 4; nt++)
                acc[mt][nt] = __builtin_amdgcn_mfma_f32_16x16x32_bf16(
                    af[mt], bfr[nt], acc[mt][nt], 0, 0, 0);
        __syncthreads();
    }
    // after final barrier As/Bs are dead; per-wave scratch (wave-private)
    u16* tr = SM + w * 1152;  // 16 rows x 72 u16

    const int hh = (n0 + wn) >> 6;
    const size_t tb = (size_t)hh * 262144 + (size_t)((m0 + wm) >> 6) * 4096;

    if (z != 2) {
        for (int mt = 0; mt < 4; mt++) {
            #pragma unroll
            for (int r = 0; r < 4; r++) {
                int m = m0 + wm + mt * 16 + quad * 4 + r;
                float v0 = acc[mt][0][r];
                float v1 = acc[mt][1][r];
                float f0 = freqs[m * 32 + l16];
                float f1 = freqs[m * 32 + 16 + l16];
                float s0, c0, s1, c1;
                __sincosf(f0, &s0, &c0);
                __sincosf(f1, &s1, &c1);
                int row = quad * 4 + r;
                tr[row * 72 + l16]      = f32_to_bf16((v0 * c0 - v1 * s0) * ascale);
                tr[row * 72 + 16 + l16] = f32_to_bf16((v1 * c1 + v0 * s1) * ascale);
                tr[row * 72 + 32 + l16] = f32_to_bf16(acc[mt][2][r] * ascale);
                tr[row * 72 + 48 + l16] = f32_to_bf16(acc[mt][3][r] * ascale);
            }
            // wave-private transpose read: lane -> row l16, cols quad*16..+16
            u16x8 va = *(const u16x8*)&tr[l16 * 72 + quad * 16];
            u16x8 vb = *(const u16x8*)&tr[l16 * 72 + quad * 16 + 8];
            if (z == 0) {
                size_t base = (size_t)(m0 + wm + mt * 16 + l16) * GN + n0 + wn + quad * 16;
                *(u16x8*)&Cb[base]     = va;
                *(u16x8*)&Cb[base + 8] = vb;
            } else {
                // K half-split: dk = quad*16 + c -> half ks = quad>>1, within = (quad&1)*16 + c
                size_t base = tb + (size_t)(quad >> 1) * 2048
                            + (size_t)(mt * 16 + l16) * 32 + (quad & 1) * 16;
                *(u16x8*)&Cb[base]     = va;
                *(u16x8*)&Cb[base + 8] = vb;
            }
        }
    } else {
        // V: VT[h][kb][ks][dv][32'], kappa within each 32-key half
        for (int mt = 0; mt < 4; mt++) {
            float o0[4], o1[4];
            for (int r = 0; r < 4; r++) {
                int m = m0 + wm + mt * 16 + quad * 4 + r;
                float v0 = acc[mt][0][r];
                float v1 = acc[mt][1][r];
                float f0 = freqs[m * 32 + l16];
                float f1 = freqs[m * 32 + 16 + l16];
                float s0, c0, s1, c1;
                __sincosf(f0, &s0, &c0);
                __sincosf(f1, &s1, &c1);
                o0[r] = v0 * c0 - v1 * s0;
                o1[r] = v1 * c1 + v0 * s1;
            }
            const int ks = mt >> 1;                       // key half
            const int sl = 4 * (mt & 1) + 8 * quad;       // slot within half (r adds 0..3)
            const size_t hb = tb + (size_t)ks * 2048 + sl;
            u16x4 u;
            u = { f32_to_bf16(o0[0]), f32_to_bf16(o0[1]), f32_to_bf16(o0[2]), f32_to_bf16(o0[3]) };
            *(u16x4*)&Cb[hb + (size_t)l16 * 32] = u;
            u = { f32_to_bf16(o1[0]), f32_to_bf16(o1[1]), f32_to_bf16(o1[2]), f32_to_bf16(o1[3]) };
            *(u16x4*)&Cb[hb + (size_t)(16 + l16) * 32] = u;
            u = { f32_to_bf16(acc[mt][2][0]), f32_to_bf16(acc[mt][2][1]),
                  f32_to_bf16(acc[mt][2][2]), f32_to_bf16(acc[mt][2][3]) };
            *(u16x4*)&Cb[hb + (size_t)(32 + l16) * 32] = u;
            u = { f32_to_bf16(acc[mt][3][0]), f32_to_bf16(acc[mt][3][1]),
                  f32_to_bf16(acc[mt][3][2]), f32_to_bf16(acc[mt][3][3]) };
            *(u16x4*)&Cb[hb + (size_t)(48 + l16) * 32] = u;
        }
    }
}

// ---------------------------------------------------------------------------
// Output projection GEMM, no split-K. Tile 64x128, grid (64 m, 8 n) = 512
// blocks = 2/CU. Full K=1024 loop, fp32 stores direct to d_out.
// ---------------------------------------------------------------------------
__global__ __launch_bounds__(256) void gemm_out(
    const u16* __restrict__ A, const u16* __restrict__ W, float* __restrict__ C)
{
    __shared__ u16 SM[8704];   // staging 6144 u16 (A 2048 | B 4096); tr 17408 B
    u16* As = SM;              // 64 x 32
    u16* Bs = SM + 2048;       // 128 x 32

    const int tid  = threadIdx.x;
    const int w    = tid >> 6;
    const int lane = tid & 63;
    const int quad = lane >> 4;
    const int l16  = lane & 15;
    const int m0 = blockIdx.x * 64;
    const int n0 = blockIdx.y * 128;
    const int wm = (w >> 1) * 32;
    const int wn = (w & 1) * 64;

    const size_t aoff  = (size_t)(m0 + (tid >> 2)) * GK + (tid & 3) * 8;
    const size_t boff0 = (size_t)(n0 + (tid >> 2)) * GK + (tid & 3) * 8;
    const size_t boff1 = boff0 + (size_t)64 * GK;
    u16* ldsA  = &As[w * 512];
    u16* ldsB0 = &Bs[w * 512];
    u16* ldsB1 = &Bs[2048 + w * 512];

    f32x4 acc[2][4];
    for (int i = 0; i < 2; i++)
        for (int j = 0; j < 4; j++) acc[i][j] = 0.f;

    for (int k0 = 0; k0 < GK; k0 += 32) {
        gl_lds16(A + aoff + k0, ldsA);
        gl_lds16(W + boff0 + k0, ldsB0);
        gl_lds16(W + boff1 + k0, ldsB1);
        __syncthreads();

        bf16x8 af[2], bfr[4];
        for (int t = 0; t < 2; t++)
            af[t] = *(const bf16x8*)&As[(wm + t * 16 + l16) * 32 + quad * 8];
        for (int t = 0; t < 4; t++)
            bfr[t] = *(const bf16x8*)&Bs[(wn + t * 16 + l16) * 32 + quad * 8];
        for (int mt = 0; mt < 2; mt++)
            for (int nt = 0; nt < 4; nt++)
                acc[mt][nt] = __builtin_amdgcn_mfma_f32_16x16x32_bf16(
                    af[mt], bfr[nt], acc[mt][nt], 0, 0, 0);
        __syncthreads();
    }

    // per-wave fp32 transpose scratch: 16 rows x 68 floats
    float* tr = (float*)SM + w * 1088;
    for (int mt = 0; mt < 2; mt++) {
        #pragma unroll
        for (int nt = 0; nt < 4; nt++)
            #pragma unroll
            for (int r = 0; r < 4; r++)
                tr[(quad * 4 + r) * 68 + nt * 16 + l16] = acc[mt][nt][r];
        size_t base = (size_t)(m0 + wm + mt * 16 + l16) * GN + n0 + wn + quad * 16;
        #pragma unroll
        for (int c = 0; c < 4; c++) {
            f32x4 v = *(const f32x4*)&tr[l16 * 68 + quad * 16 + c * 4];
            *(f32x4*)&C[base + c * 4] = v;
        }
    }
}

// ---------------------------------------------------------------------------
// Flash attention, causal. Grid 512 x 256 thr (4 waves).
// Block = (head h, idx): p = idx<16 ? idx : 47-idx. Waves 0,1 own q-tile
// 63-p (32 q rows each, full key stream kb=0..63-p); waves 2,3 own q-tile p
// (same shared K/V stream, early-exit past kb=p). Block length = 64-p iters;
// the p(idx) remap makes co-resident block pairs {idx, idx+16} sum to a
// CONSTANT 97 iters per CU (static perfect balance, same-head pairing).
// Each wave: 32 q rows = 2 Q B-frags -> every K/V ds_read_b128 feeds 2 MFMAs.
// K/V staged per block via global_load_lds into 32 KB LDS double buffer, DMA
// for kb+1 issued right after the top barrier. Fixed-max softmax (exp(s-16));
// P repacked register-only into PV B-operand (V pre-permuted per 32-key half).
// ---------------------------------------------------------------------------
__global__ __launch_bounds__(256, 2) void attn_kernel(
    const u16* __restrict__ Qb, const u16* __restrict__ KT,
    const u16* __restrict__ VTg, u16* __restrict__ valsb)
{
    __shared__ u16 KV[2][8192];      // [buf][ K 4096 | V 4096 ] u16
    __shared__ float Ow[4][16 * 68]; // per-wave epilogue transpose (2 passes)

    const int tid  = threadIdx.x;
    const int w    = tid >> 6;
    const int lane = tid & 63;
    const int quad = lane >> 4;
    const int l16  = lane & 15;
    const int HD = 1024;

    const int id  = blockIdx.x;
    const int h   = (id & 7) * 2 + ((id >> 3) & 1);
    const int idx = id >> 4;                         // 0..31
    const int p   = (idx < 16) ? idx : (47 - idx);   // balance remap
    const int jt  = (w < 2) ? (63 - p) : p;          // this wave's 64-row q-tile
    const int kb_end = 63 - p;                       // stream length - 1
    const int kb_me  = (w < 2) ? (63 - p) : p;       // my last active (diag) tile
    const int qbase  = (w & 1) * 32;                 // row offset within tile

    const u16* kt = KT  + (size_t)h * 262144;
    const u16* vt = VTg + (size_t)h * 262144;

    // Q B-frags: rows jt*64 + qbase + qt*16 + l16
    bf16x8 bq[2][2];
    #pragma unroll
    for (int qt = 0; qt < 2; qt++)
        #pragma unroll
        for (int ks = 0; ks < 2; ks++)
            bq[qt][ks] = *(const bf16x8*)&Qb[(size_t)(jt * 64 + qbase + qt * 16 + l16) * HD
                                             + h * 64 + ks * 32 + quad * 8];

    f32x4 o[2][4];
    #pragma unroll
    for (int qt = 0; qt < 2; qt++)
        #pragma unroll
        for (int nv = 0; nv < 4; nv++) o[qt][nv] = 0.f;
    float lsum[2] = { 0.f, 0.f };

    // prologue DMA: tile 0 -> buf 0
    #pragma unroll
    for (int i = 0; i < 2; i++) {
        gl_lds16(kt + i * 2048 + w * 512 + lane * 8, &KV[0][i * 2048 + w * 512]);
        gl_lds16(vt + i * 2048 + w * 512 + lane * 8, &KV[0][4096 + i * 2048 + w * 512]);
    }

    for (int kb = 0; kb <= kb_end; kb++) {
        __syncthreads();  // DMA for kb drained; buf[(kb+1)&1] free
        if (kb < kb_end) {
            const int nb = (kb + 1) & 1;
            const u16* ksrc = kt + (size_t)(kb + 1) * 4096;
            const u16* vsrc = vt + (size_t)(kb + 1) * 4096;
            #pragma unroll
            for (int i = 0; i < 2; i++) {
                gl_lds16(ksrc + i * 2048 + w * 512 + lane * 8, &KV[nb][i * 2048 + w * 512]);
                gl_lds16(vsrc + i * 2048 + w * 512 + lane * 8, &KV[nb][4096 + i * 2048 + w * 512]);
            }
        }
        if (kb > kb_me) continue;  // waves 2,3 done past their diagonal

        const u16* Ksb = &KV[kb & 1][0];
        const u16* Vsb = &KV[kb & 1][4096];

        // S^T = K * Q^T : key = nt*16 + quad*4 + r, q = qt*16 + l16
        f32x4 s[2][4];
        #pragma unroll
        for (int nt = 0; nt < 4; nt++) {
            bf16x8 ak0 = *(const bf16x8*)&Ksb[(nt * 16 + l16) * 32 + quad * 8];
            bf16x8 ak1 = *(const bf16x8*)&Ksb[2048 + (nt * 16 + l16) * 32 + quad * 8];
            #pragma unroll
            for (int qt = 0; qt < 2; qt++) {
                f32x4 z4 = { 0.f, 0.f, 0.f, 0.f };
                s[qt][nt] = __builtin_amdgcn_mfma_f32_16x16x32_bf16(ak0, bq[qt][0], z4, 0, 0, 0);
                s[qt][nt] = __builtin_amdgcn_mfma_f32_16x16x32_bf16(ak1, bq[qt][1], s[qt][nt], 0, 0, 0);
            }
        }

        if (kb == kb_me) {  // diagonal tile: mask key > q
            #pragma unroll
            for (int qt = 0; qt < 2; qt++) {
                const int ql = qbase + qt * 16 + l16;
                #pragma unroll
                for (int nt = 0; nt < 4; nt++)
                    #pragma unroll
                    for (int r = 0; r < 4; r++)
                        if (nt * 16 + quad * 4 + r > ql) s[qt][nt][r] = -1e30f;
            }
        }

        // V frags issued before exp so lgkmcnt hides under VALU
        bf16x8 av[8];
        #pragma unroll
        for (int nv = 0; nv < 4; nv++) {
            av[nv * 2]     = *(const bf16x8*)&Vsb[(nv * 16 + l16) * 32 + quad * 8];
            av[nv * 2 + 1] = *(const bf16x8*)&Vsb[2048 + (nv * 16 + l16) * 32 + quad * 8];
        }

        #pragma unroll
        for (int qt = 0; qt < 2; qt++) {
            float ls = 0.f;
            #pragma unroll
            for (int nt = 0; nt < 4; nt++)
                #pragma unroll
                for (int r = 0; r < 4; r++) {
                    float pe = __expf(s[qt][nt][r] - 16.f);
                    s[qt][nt][r] = pe;
                    ls += pe;
                }
            lsum[qt] += ls;

            bf16x8 bp0 = { f32_to_bf16_trunc(s[qt][0][0]), f32_to_bf16_trunc(s[qt][0][1]),
                           f32_to_bf16_trunc(s[qt][0][2]), f32_to_bf16_trunc(s[qt][0][3]),
                           f32_to_bf16_trunc(s[qt][1][0]), f32_to_bf16_trunc(s[qt][1][1]),
                           f32_to_bf16_trunc(s[qt][1][2]), f32_to_bf16_trunc(s[qt][1][3]) };
            bf16x8 bp1 = { f32_to_bf16_trunc(s[qt][2][0]), f32_to_bf16_trunc(s[qt][2][1]),
                           f32_to_bf16_trunc(s[qt][2][2]), f32_to_bf16_trunc(s[qt][2][3]),
                           f32_to_bf16_trunc(s[qt][3][0]), f32_to_bf16_trunc(s[qt][3][1]),
                           f32_to_bf16_trunc(s[qt][3][2]), f32_to_bf16_trunc(s[qt][3][3]) };
            #pragma unroll
            for (int nv = 0; nv < 4; nv++) {
                o[qt][nv] = __builtin_amdgcn_mfma_f32_16x16x32_bf16(av[nv * 2], bp0, o[qt][nv], 0, 0, 0);
                o[qt][nv] = __builtin_amdgcn_mfma_f32_16x16x32_bf16(av[nv * 2 + 1], bp1, o[qt][nv], 0, 0, 0);
            }
        }
    }

    // epilogue: per-wave LDS transpose, 16 rows per pass (wave-private)
    float* myOw = Ow[w];
    #pragma unroll
    for (int qt = 0; qt < 2; qt++) {
        float ls = lsum[qt];
        ls += __shfl_xor(ls, 16);
        ls += __shfl_xor(ls, 32);
        const float linv = 1.f / ls;
        #pragma unroll
        for (int nv = 0; nv < 4; nv++)
            #pragma unroll
            for (int r = 0; r < 4; r++)
                myOw[l16 * 68 + nv * 16 + quad * 4 + r] = o[qt][nv][r] * linv;
        #pragma unroll
        for (int i = 0; i < 4; i++) {
            int row = i * 4 + quad;  // row within this 16-row pass
            f32x4 vv = *(const f32x4*)&myOw[row * 68 + l16 * 4];
            u16x4 u = { f32_to_bf16(vv[0]), f32_to_bf16(vv[1]), f32_to_bf16(vv[2]), f32_to_bf16(vv[3]) };
            *(u16x4*)&valsb[(size_t)(jt * 64 + qbase + qt * 16 + row) * HD + h * 64 + l16 * 4] = u;
        }
    }
}

// ---------------------------------------------------------------------------
// ws layout (u16 idx): qc 0 | kc 4M | vc 8M | wqc 12M | wkc 13M | wvc 14M |
// woc 15M | Qb 16M | KT 20M | VT 24M ; valsb reuses qc. Total 56 MiB.
// ---------------------------------------------------------------------------
extern "C" void kernel_launch(void* const* d_in, const int* in_sizes, int n_in,
                              void* d_out, int out_size, void* d_ws, size_t ws_size,
                              hipStream_t stream) {
    const float* q     = (const float*)d_in[0];
    const float* k     = (const float*)d_in[1];
    const float* v     = (const float*)d_in[2];
    const float* freqs = (const float*)d_in[4];
    const float* wq    = (const float*)d_in[5];
    const float* wk    = (const float*)d_in[6];
    const float* wv    = (const float*)d_in[7];
    const float* wo    = (const float*)d_in[8];

    u16* B = (u16*)d_ws;
    u16* qc  = B;
    u16* kc  = B + (size_t)4194304;
    u16* vc  = B + (size_t)8388608;
    u16* wqc = B + (size_t)12582912;
    u16* wkc = B + (size_t)13631488;
    u16* wvc = B + (size_t)14680064;
    u16* woc = B + (size_t)15728640;
    u16* Qb  = B + (size_t)16777216;
    u16* KT  = B + (size_t)20971520;
    u16* VT  = B + (size_t)25165824;
    u16* valsb = qc;   // qc dead after gemm_rope reads it

    CastArgs ca;
    ca.src[0] = q;  ca.dst[0] = qc;  ca.n4[0] = 1048576;
    ca.src[1] = k;  ca.dst[1] = kc;  ca.n4[1] = 1048576;
    ca.src[2] = v;  ca.dst[2] = vc;  ca.n4[2] = 1048576;
    ca.src[3] = wq; ca.dst[3] = wqc; ca.n4[3] = 262144;
    ca.src[4] = wk; ca.dst[4] = wkc; ca.n4[4] = 262144;
    ca.src[5] = wv; ca.dst[5] = wvc; ca.n4[5] = 262144;
    ca.src[6] = wo; ca.dst[6] = woc; ca.n4[6] = 262144;
    cast_kernel<<<dim3(1024, 7), 256, 0, stream>>>(ca);

    gemm_rope<<<dim3(32, 8, 3), 256, 0, stream>>>(
        qc, kc, vc, wqc, wkc, wvc, Qb, KT, VT, freqs);

    attn_kernel<<<dim3(512), 256, 0, stream>>>(Qb, KT, VT, valsb);

    gemm_out<<<dim3(64, 8), 256, 0, stream>>>(valsb, woc, (float*)d_out);
}

// Round 9
// 272.237 us; speedup vs baseline: 1.0639x; 1.0617x over previous
//
#include <hip/hip_runtime.h>

typedef unsigned short u16;
typedef unsigned int u32;
typedef short bf16x8 __attribute__((ext_vector_type(8)));
typedef float f32x4 __attribute__((ext_vector_type(4)));
typedef unsigned short u16x4 __attribute__((ext_vector_type(4)));
typedef unsigned short u16x8 __attribute__((ext_vector_type(8)));

__device__ __forceinline__ u16 f32_to_bf16(float f) {
    u32 u = __float_as_uint(f);
    u += 0x7FFFu + ((u >> 16) & 1u);
    return (u16)(u >> 16);
}
// truncating cast (p in [0,1], P-matrix only)
__device__ __forceinline__ short f32_to_bf16_trunc(float f) {
    return (short)(__float_as_uint(f) >> 16);
}

// async global->LDS, 16B per lane; lds pointer must be wave-uniform
__device__ __forceinline__ void gl_lds16(const u16* g, u16* l) {
    __builtin_amdgcn_global_load_lds(
        (const __attribute__((address_space(1))) u32*)g,
        (__attribute__((address_space(3))) u32*)l, 16, 0, 0);
}

// Bank-conflict swizzle for 64B-row LDS tiles read as (row*32 + chunk*8) u16:
// physical chunk = logical chunk ^ ((row>>1)&3). Folded into the DMA *source*
// address (per-lane), so LDS writes stay contiguous. Makes each 8-lane phase
// of a ds_read_b128 hit all 8 bank groups (was 4-way conflicted).

// ---------------------------------------------------------------------------
// bulk fp32 -> bf16 cast
// ---------------------------------------------------------------------------
struct CastArgs {
    const float* src[7];
    u16* dst[7];
    int n4[7];
};

__global__ __launch_bounds__(256) void cast_kernel(CastArgs a) {
    const int y = blockIdx.y;
    const float* s = a.src[y];
    u16* d = a.dst[y];
    const int n4 = a.n4[y];
    for (int i = blockIdx.x * blockDim.x + threadIdx.x; i < n4; i += gridDim.x * blockDim.x) {
        f32x4 v = *(const f32x4*)&s[(size_t)i * 4];
        u16x4 o = { f32_to_bf16(v[0]), f32_to_bf16(v[1]), f32_to_bf16(v[2]), f32_to_bf16(v[3]) };
        *(u16x4*)&d[(size_t)i * 4] = o;
    }
}

#define GK 1024
#define GN 1024
#define GM 4096

// ---------------------------------------------------------------------------
// QKV projection GEMM + RoPE. 128x128 tile, BK=32, grid (32 m, 8 n, 3 z).
// z=0 Q: normal [t][HD] bf16, scaled 1/8.
// z=1 K: KT[h][kb][ks][kl][32]   (dk halves ks -> 64 B rows)
// z=2 V: VT[h][kb][ks][dv][32']  (key halves; kappa permutation in slot idx)
// LDS staging/read pair uses the XOR bank swizzle.
// ---------------------------------------------------------------------------
__global__ __launch_bounds__(256) void gemm_rope(
    const u16* __restrict__ A0, const u16* __restrict__ A1, const u16* __restrict__ A2,
    const u16* __restrict__ W0, const u16* __restrict__ W1, const u16* __restrict__ W2,
    u16* __restrict__ C0, u16* __restrict__ C1, u16* __restrict__ C2,
    const float* __restrict__ freqs)
{
    __shared__ u16 SM[8192];
    u16* As = SM;
    u16* Bs = SM + 4096;

    const int z = blockIdx.z;
    const u16* A = (z == 0) ? A0 : ((z == 1) ? A1 : A2);
    const u16* W = (z == 0) ? W0 : ((z == 1) ? W1 : W2);
    u16* Cb      = (z == 0) ? C0 : ((z == 1) ? C1 : C2);
    const float ascale = (z == 0) ? 0.125f : 1.0f;

    const int tid  = threadIdx.x;
    const int w    = tid >> 6;
    const int lane = tid & 63;
    const int quad = lane >> 4;
    const int l16  = lane & 15;
    const int m0 = blockIdx.x * 128;
    const int n0 = blockIdx.y * 128;
    const int wm = (w >> 1) * 64;
    const int wn = (w & 1) * 64;

    const int sr = tid >> 2;
    const int sc = (((tid & 3) ^ ((tid >> 3) & 3))) * 8;   // swizzled source chunk
    const size_t aoff0 = (size_t)(m0 + sr) * GK + sc;
    const size_t aoff1 = aoff0 + (size_t)64 * GK;
    const size_t boff0 = (size_t)(n0 + sr) * GK + sc;
    const size_t boff1 = boff0 + (size_t)64 * GK;
    u16* ldsA0 = &As[w * 512];
    u16* ldsA1 = &As[2048 + w * 512];
    u16* ldsB0 = &Bs[w * 512];
    u16* ldsB1 = &Bs[2048 + w * 512];

    const int csw = (quad ^ ((l16 >> 1) & 3)) * 8;          // swizzled read chunk

    f32x4 acc[4][4];
    for (int i = 0; i < 4; i++)
        for (int j = 0; j < 4; j++) acc[i][j] = 0.f;

    for (int k0 = 0; k0 < GK; k0 += 32) {
        gl_lds16(A + aoff0 + k0, ldsA0);
        gl_lds16(A + aoff1 + k0, ldsA1);
        gl_lds16(W + boff0 + k0, ldsB0);
        gl_lds16(W + boff1 + k0, ldsB1);
        __syncthreads();

        bf16x8 af[4], bfr[4];
        for (int t = 0; t < 4; t++) {
            af[t]  = *(const bf16x8*)&As[(wm + t * 16 + l16) * 32 + csw];
            bfr[t] = *(const bf16x8*)&Bs[(wn + t * 16 + l16) * 32 + csw];
        }
        for (int mt = 0; mt < 4; mt++)
            for (int nt = 0; nt < 4; nt++)
                acc[mt][nt] = __builtin_amdgcn_mfma_f32_16x16x32_bf16(
                    af[mt], bfr[nt], acc[mt][nt], 0, 0, 0);
        __syncthreads();
    }
    // after final barrier As/Bs are dead; per-wave scratch (wave-private)
    u16* tr = SM + w * 1152;  // 16 rows x 72 u16

    const int hh = (n0 + wn) >> 6;
    const size_t tb = (size_t)hh * 262144 + (size_t)((m0 + wm) >> 6) * 4096;

    if (z != 2) {
        for (int mt = 0; mt < 4; mt++) {
            #pragma unroll
            for (int r = 0; r < 4; r++) {
                int m = m0 + wm + mt * 16 + quad * 4 + r;
                float v0 = acc[mt][0][r];
                float v1 = acc[mt][1][r];
                float f0 = freqs[m * 32 + l16];
                float f1 = freqs[m * 32 + 16 + l16];
                float s0, c0, s1, c1;
                __sincosf(f0, &s0, &c0);
                __sincosf(f1, &s1, &c1);
                int row = quad * 4 + r;
                tr[row * 72 + l16]      = f32_to_bf16((v0 * c0 - v1 * s0) * ascale);
                tr[row * 72 + 16 + l16] = f32_to_bf16((v1 * c1 + v0 * s1) * ascale);
                tr[row * 72 + 32 + l16] = f32_to_bf16(acc[mt][2][r] * ascale);
                tr[row * 72 + 48 + l16] = f32_to_bf16(acc[mt][3][r] * ascale);
            }
            // wave-private transpose read: lane -> row l16, cols quad*16..+16
            u16x8 va = *(const u16x8*)&tr[l16 * 72 + quad * 16];
            u16x8 vb = *(const u16x8*)&tr[l16 * 72 + quad * 16 + 8];
            if (z == 0) {
                size_t base = (size_t)(m0 + wm + mt * 16 + l16) * GN + n0 + wn + quad * 16;
                *(u16x8*)&Cb[base]     = va;
                *(u16x8*)&Cb[base + 8] = vb;
            } else {
                // K half-split: dk = quad*16 + c -> half ks = quad>>1, within = (quad&1)*16 + c
                size_t base = tb + (size_t)(quad >> 1) * 2048
                            + (size_t)(mt * 16 + l16) * 32 + (quad & 1) * 16;
                *(u16x8*)&Cb[base]     = va;
                *(u16x8*)&Cb[base + 8] = vb;
            }
        }
    } else {
        // V: VT[h][kb][ks][dv][32'], kappa within each 32-key half
        for (int mt = 0; mt < 4; mt++) {
            float o0[4], o1[4];
            for (int r = 0; r < 4; r++) {
                int m = m0 + wm + mt * 16 + quad * 4 + r;
                float v0 = acc[mt][0][r];
                float v1 = acc[mt][1][r];
                float f0 = freqs[m * 32 + l16];
                float f1 = freqs[m * 32 + 16 + l16];
                float s0, c0, s1, c1;
                __sincosf(f0, &s0, &c0);
                __sincosf(f1, &s1, &c1);
                o0[r] = v0 * c0 - v1 * s0;
                o1[r] = v1 * c1 + v0 * s1;
            }
            const int ks = mt >> 1;                       // key half
            const int sl = 4 * (mt & 1) + 8 * quad;       // slot within half (r adds 0..3)
            const size_t hb = tb + (size_t)ks * 2048 + sl;
            u16x4 u;
            u = { f32_to_bf16(o0[0]), f32_to_bf16(o0[1]), f32_to_bf16(o0[2]), f32_to_bf16(o0[3]) };
            *(u16x4*)&Cb[hb + (size_t)l16 * 32] = u;
            u = { f32_to_bf16(o1[0]), f32_to_bf16(o1[1]), f32_to_bf16(o1[2]), f32_to_bf16(o1[3]) };
            *(u16x4*)&Cb[hb + (size_t)(16 + l16) * 32] = u;
            u = { f32_to_bf16(acc[mt][2][0]), f32_to_bf16(acc[mt][2][1]),
                  f32_to_bf16(acc[mt][2][2]), f32_to_bf16(acc[mt][2][3]) };
            *(u16x4*)&Cb[hb + (size_t)(32 + l16) * 32] = u;
            u = { f32_to_bf16(acc[mt][3][0]), f32_to_bf16(acc[mt][3][1]),
                  f32_to_bf16(acc[mt][3][2]), f32_to_bf16(acc[mt][3][3]) };
            *(u16x4*)&Cb[hb + (size_t)(48 + l16) * 32] = u;
        }
    }
}

// ---------------------------------------------------------------------------
// Output projection GEMM. Tile 64x128, grid (64 m, 8 n) = 512 blocks = 2/CU.
// Full K=1024, fp32 stores direct to d_out. XOR bank swizzle on staging/reads.
// ---------------------------------------------------------------------------
__global__ __launch_bounds__(256) void gemm_out(
    const u16* __restrict__ A, const u16* __restrict__ W, float* __restrict__ C)
{
    __shared__ u16 SM[8704];   // staging 6144 u16 (A 2048 | B 4096); tr 17408 B
    u16* As = SM;              // 64 x 32
    u16* Bs = SM + 2048;       // 128 x 32

    const int tid  = threadIdx.x;
    const int w    = tid >> 6;
    const int lane = tid & 63;
    const int quad = lane >> 4;
    const int l16  = lane & 15;
    const int m0 = blockIdx.x * 64;
    const int n0 = blockIdx.y * 128;
    const int wm = (w >> 1) * 32;
    const int wn = (w & 1) * 64;

    const int sr = tid >> 2;
    const int sc = (((tid & 3) ^ ((tid >> 3) & 3))) * 8;   // swizzled source chunk
    const size_t aoff  = (size_t)(m0 + sr) * GK + sc;
    const size_t boff0 = (size_t)(n0 + sr) * GK + sc;
    const size_t boff1 = boff0 + (size_t)64 * GK;
    u16* ldsA  = &As[w * 512];
    u16* ldsB0 = &Bs[w * 512];
    u16* ldsB1 = &Bs[2048 + w * 512];

    const int csw = (quad ^ ((l16 >> 1) & 3)) * 8;

    f32x4 acc[2][4];
    for (int i = 0; i < 2; i++)
        for (int j = 0; j < 4; j++) acc[i][j] = 0.f;

    for (int k0 = 0; k0 < GK; k0 += 32) {
        gl_lds16(A + aoff + k0, ldsA);
        gl_lds16(W + boff0 + k0, ldsB0);
        gl_lds16(W + boff1 + k0, ldsB1);
        __syncthreads();

        bf16x8 af[2], bfr[4];
        for (int t = 0; t < 2; t++)
            af[t] = *(const bf16x8*)&As[(wm + t * 16 + l16) * 32 + csw];
        for (int t = 0; t < 4; t++)
            bfr[t] = *(const bf16x8*)&Bs[(wn + t * 16 + l16) * 32 + csw];
        for (int mt = 0; mt < 2; mt++)
            for (int nt = 0; nt < 4; nt++)
                acc[mt][nt] = __builtin_amdgcn_mfma_f32_16x16x32_bf16(
                    af[mt], bfr[nt], acc[mt][nt], 0, 0, 0);
        __syncthreads();
    }

    // per-wave fp32 transpose scratch: 16 rows x 68 floats
    float* tr = (float*)SM + w * 1088;
    for (int mt = 0; mt < 2; mt++) {
        #pragma unroll
        for (int nt = 0; nt < 4; nt++)
            #pragma unroll
            for (int r = 0; r < 4; r++)
                tr[(quad * 4 + r) * 68 + nt * 16 + l16] = acc[mt][nt][r];
        size_t base = (size_t)(m0 + wm + mt * 16 + l16) * GN + n0 + wn + quad * 16;
        #pragma unroll
        for (int c = 0; c < 4; c++) {
            f32x4 v = *(const f32x4*)&tr[l16 * 68 + quad * 16 + c * 4];
            *(f32x4*)&C[base + c * 4] = v;
        }
    }
}

// ---------------------------------------------------------------------------
// Flash attention, causal (round-6 structure + XOR bank swizzle).
// Grid 512 x 256 thr (4 waves). Block = (head h, pair {p, 63-p}) processed
// sequentially -> 65 iters/block constant, all 4 waves active every iter.
// Wave w owns q rows [qb*64 + 16w, +16). K/V staged per block via
// global_load_lds into a 32 KB LDS double buffer; DMA for kb+1 issued right
// after the top barrier. One barrier/iter. Fixed-max softmax (exp(s-16));
// P repacked register-only into PV B-operand (V pre-permuted per 32-half).
// ---------------------------------------------------------------------------
__global__ __launch_bounds__(256, 2) void attn_kernel(
    const u16* __restrict__ Qb, const u16* __restrict__ KT,
    const u16* __restrict__ VTg, u16* __restrict__ valsb)
{
    __shared__ u16 KV[2][8192];      // [buf][ K 4096 | V 4096 ] u16
    __shared__ float Ow[4][16 * 68];

    const int tid  = threadIdx.x;
    const int w    = tid >> 6;
    const int lane = tid & 63;
    const int quad = lane >> 4;
    const int l16  = lane & 15;
    const int HD = 1024;

    const int id = blockIdx.x;
    const int h  = (id & 7) * 2 + ((id >> 3) & 1);
    const int p  = id >> 4;                    // 0..31

    const u16* kt = KT  + (size_t)h * 262144;
    const u16* vt = VTg + (size_t)h * 262144;

    // swizzled per-lane DMA source offset within a 1KB (16-row) span:
    // phys (row rr=lane>>2, chunk c=lane&3) fetches logical chunk c^((rr>>1)&3)
    const int dmaoff = (lane >> 2) * 32 + ((lane & 3) ^ ((lane >> 3) & 3)) * 8;
    const int csw = (quad ^ ((l16 >> 1) & 3)) * 8;   // swizzled read chunk

    for (int gi = 0; gi < 2; gi++) {
        const int qb = gi ? (63 - p) : p;

        // Q B-frags for this wave's 16 q rows (global, unswizzled)
        const size_t qrow = (size_t)(qb * 64 + w * 16 + l16);
        bf16x8 bq0 = *(const bf16x8*)&Qb[qrow * HD + h * 64 + quad * 8];
        bf16x8 bq1 = *(const bf16x8*)&Qb[qrow * HD + h * 64 + 32 + quad * 8];

        f32x4 o[4];
        #pragma unroll
        for (int i = 0; i < 4; i++) o[i] = 0.f;
        float lsum = 0.f;
        const int q_local = w * 16 + l16;

        // ensure no wave is still reading KV from the previous phase
        __syncthreads();
        // prologue DMA: tile 0 -> buf 0
        #pragma unroll
        for (int i = 0; i < 2; i++) {
            gl_lds16(kt + i * 2048 + w * 512 + dmaoff, &KV[0][i * 2048 + w * 512]);
            gl_lds16(vt + i * 2048 + w * 512 + dmaoff, &KV[0][4096 + i * 2048 + w * 512]);
        }

        for (int kb = 0; kb <= qb; kb++) {
            __syncthreads();  // DMA for kb drained; buf[(kb+1)&1] free
            if (kb < qb) {
                const int nb = (kb + 1) & 1;
                const u16* ksrc = kt + (size_t)(kb + 1) * 4096;
                const u16* vsrc = vt + (size_t)(kb + 1) * 4096;
                #pragma unroll
                for (int i = 0; i < 2; i++) {
                    gl_lds16(ksrc + i * 2048 + w * 512 + dmaoff, &KV[nb][i * 2048 + w * 512]);
                    gl_lds16(vsrc + i * 2048 + w * 512 + dmaoff, &KV[nb][4096 + i * 2048 + w * 512]);
                }
            }
            const u16* Ksb = &KV[kb & 1][0];
            const u16* Vsb = &KV[kb & 1][4096];

            // S^T = K * Q^T : lane q = l16, key = nt2*16 + quad*4 + r
            f32x4 s[4];
            #pragma unroll
            for (int nt2 = 0; nt2 < 4; nt2++) {
                bf16x8 ak0 = *(const bf16x8*)&Ksb[(nt2 * 16 + l16) * 32 + csw];
                bf16x8 ak1 = *(const bf16x8*)&Ksb[2048 + (nt2 * 16 + l16) * 32 + csw];
                f32x4 z4 = { 0.f, 0.f, 0.f, 0.f };
                s[nt2] = __builtin_amdgcn_mfma_f32_16x16x32_bf16(ak0, bq0, z4, 0, 0, 0);
                s[nt2] = __builtin_amdgcn_mfma_f32_16x16x32_bf16(ak1, bq1, s[nt2], 0, 0, 0);
            }

            if (kb == qb) {  // diagonal: mask key > q
                #pragma unroll
                for (int nt2 = 0; nt2 < 4; nt2++)
                    #pragma unroll
                    for (int r = 0; r < 4; r++)
                        if (nt2 * 16 + quad * 4 + r > q_local) s[nt2][r] = -1e30f;
            }

            // V frags issued before exp so lgkmcnt hides under VALU
            bf16x8 av[8];
            #pragma unroll
            for (int nv = 0; nv < 4; nv++) {
                av[nv * 2]     = *(const bf16x8*)&Vsb[(nv * 16 + l16) * 32 + csw];
                av[nv * 2 + 1] = *(const bf16x8*)&Vsb[2048 + (nv * 16 + l16) * 32 + csw];
            }

            #pragma unroll
            for (int nt2 = 0; nt2 < 4; nt2++)
                #pragma unroll
                for (int r = 0; r < 4; r++) {
                    float pe = __expf(s[nt2][r] - 16.f);
                    s[nt2][r] = pe;
                    lsum += pe;
                }

            bf16x8 bp0 = { f32_to_bf16_trunc(s[0][0]), f32_to_bf16_trunc(s[0][1]),
                           f32_to_bf16_trunc(s[0][2]), f32_to_bf16_trunc(s[0][3]),
                           f32_to_bf16_trunc(s[1][0]), f32_to_bf16_trunc(s[1][1]),
                           f32_to_bf16_trunc(s[1][2]), f32_to_bf16_trunc(s[1][3]) };
            bf16x8 bp1 = { f32_to_bf16_trunc(s[2][0]), f32_to_bf16_trunc(s[2][1]),
                           f32_to_bf16_trunc(s[2][2]), f32_to_bf16_trunc(s[2][3]),
                           f32_to_bf16_trunc(s[3][0]), f32_to_bf16_trunc(s[3][1]),
                           f32_to_bf16_trunc(s[3][2]), f32_to_bf16_trunc(s[3][3]) };
            #pragma unroll
            for (int nv = 0; nv < 4; nv++) {
                o[nv] = __builtin_amdgcn_mfma_f32_16x16x32_bf16(av[nv * 2], bp0, o[nv], 0, 0, 0);
                o[nv] = __builtin_amdgcn_mfma_f32_16x16x32_bf16(av[nv * 2 + 1], bp1, o[nv], 0, 0, 0);
            }
        }

        // epilogue (wave-private scratch, no barrier needed)
        lsum += __shfl_xor(lsum, 16);
        lsum += __shfl_xor(lsum, 32);
        const float inv = 1.f / lsum;
        float* myOw = Ow[w];
        #pragma unroll
        for (int nv = 0; nv < 4; nv++)
            #pragma unroll
            for (int r = 0; r < 4; r++)
                myOw[l16 * 68 + nv * 16 + quad * 4 + r] = o[nv][r] * inv;
        #pragma unroll
        for (int i = 0; i < 4; i++) {
            int row = i * 4 + quad;   // q row within wave's 16
            f32x4 vv = *(const f32x4*)&myOw[row * 68 + l16 * 4];
            u16x4 u = { f32_to_bf16(vv[0]), f32_to_bf16(vv[1]), f32_to_bf16(vv[2]), f32_to_bf16(vv[3]) };
            *(u16x4*)&valsb[(size_t)(qb * 64 + w * 16 + row) * HD + h * 64 + l16 * 4] = u;
        }
    }
}

// ---------------------------------------------------------------------------
// ws layout (u16 idx): qc 0 | kc 4M | vc 8M | wqc 12M | wkc 13M | wvc 14M |
// woc 15M | Qb 16M | KT 20M | VT 24M ; valsb reuses qc. Total 56 MiB.
// ---------------------------------------------------------------------------
extern "C" void kernel_launch(void* const* d_in, const int* in_sizes, int n_in,
                              void* d_out, int out_size, void* d_ws, size_t ws_size,
                              hipStream_t stream) {
    const float* q     = (const float*)d_in[0];
    const float* k     = (const float*)d_in[1];
    const float* v     = (const float*)d_in[2];
    const float* freqs = (const float*)d_in[4];
    const float* wq    = (const float*)d_in[5];
    const float* wk    = (const float*)d_in[6];
    const float* wv    = (const float*)d_in[7];
    const float* wo    = (const float*)d_in[8];

    u16* B = (u16*)d_ws;
    u16* qc  = B;
    u16* kc  = B + (size_t)4194304;
    u16* vc  = B + (size_t)8388608;
    u16* wqc = B + (size_t)12582912;
    u16* wkc = B + (size_t)13631488;
    u16* wvc = B + (size_t)14680064;
    u16* woc = B + (size_t)15728640;
    u16* Qb  = B + (size_t)16777216;
    u16* KT  = B + (size_t)20971520;
    u16* VT  = B + (size_t)25165824;
    u16* valsb = qc;   // qc dead after gemm_rope reads it

    CastArgs ca;
    ca.src[0] = q;  ca.dst[0] = qc;  ca.n4[0] = 1048576;
    ca.src[1] = k;  ca.dst[1] = kc;  ca.n4[1] = 1048576;
    ca.src[2] = v;  ca.dst[2] = vc;  ca.n4[2] = 1048576;
    ca.src[3] = wq; ca.dst[3] = wqc; ca.n4[3] = 262144;
    ca.src[4] = wk; ca.dst[4] = wkc; ca.n4[4] = 262144;
    ca.src[5] = wv; ca.dst[5] = wvc; ca.n4[5] = 262144;
    ca.src[6] = wo; ca.dst[6] = woc; ca.n4[6] = 262144;
    cast_kernel<<<dim3(1024, 7), 256, 0, stream>>>(ca);

    gemm_rope<<<dim3(32, 8, 3), 256, 0, stream>>>(
        qc, kc, vc, wqc, wkc, wvc, Qb, KT, VT, freqs);

    attn_kernel<<<dim3(512), 256, 0, stream>>>(Qb, KT, VT, valsb);

    gemm_out<<<dim3(64, 8), 256, 0, stream>>>(valsb, woc, (float*)d_out);
}